// Round 1
// baseline (5442.741 us; speedup 1.0000x reference)
//
#include <hip/hip_runtime.h>
#include <hip/hip_bf16.h>
#include <math.h>

// Problem constants
#define BATCH 8
#define CH 48
#define HH 256
#define WW 256
#define NPROMPT 16
#define NEXP 8
#define NGRP 4
#define GDIM 12   // CH / NGRP
#define HW (HH * WW)

// ---------------------------------------------------------------------------
// Kernel 1: fold branch-a (prompt-conditioned 1x1 + fi_align) and branch-b
// (1x1 + depthwise 3x3) into a single per-batch 3x3 conv weight W_fx.
// Layout: W_fx[b][cin][cout][tap]  (cin-major so the compute kernel reads a
// contiguous 432-float run of wave-uniform weights per input channel).
// Also zeroes the gap accumulator.
// ---------------------------------------------------------------------------
__global__ __launch_bounds__(256) void precompute_kernel(
    const float* __restrict__ P_hat,      // [B,16,48]
    const float* __restrict__ proj_a_w,   // [48,48]
    const float* __restrict__ proj_b_w,   // [48,48]
    const float* __restrict__ dw_b_w,     // [48,9]
    const float* __restrict__ fi_align_w, // [48,4]
    float* __restrict__ Wfx,              // [B,48,48,9]
    float* __restrict__ gap)              // [B,48]
{
    int b = blockIdx.x;
    int tid = threadIdx.x;
    __shared__ float p_avg[CH];
    __shared__ float W_fi[NGRP * CH];   // [g][k]
    __shared__ float W_a[CH * CH];      // [o][k]

    if (tid < CH) {
        float s = 0.f;
        for (int n = 0; n < NPROMPT; n++)
            s += P_hat[(b * NPROMPT + n) * CH + tid];
        p_avg[tid] = s * (1.0f / NPROMPT);
    }
    if (b == 0) {
        for (int i = tid; i < BATCH * CH; i += 256) gap[i] = 0.f;
    }
    __syncthreads();

    if (tid < NGRP * CH) {
        int g = tid / CH, k = tid % CH;
        float s = 0.f;
        for (int j = 0; j < GDIM; j++) {
            int c = g * GDIM + j;
            s += p_avg[c] * proj_a_w[c * CH + k];
        }
        W_fi[tid] = s;
    }
    __syncthreads();

    for (int e = tid; e < CH * CH; e += 256) {
        int o = e / CH, k = e % CH;
        float s = 0.f;
        for (int g = 0; g < NGRP; g++)
            s += fi_align_w[o * NGRP + g] * W_fi[g * CH + k];
        W_a[e] = s;
    }
    __syncthreads();

    // W_fx[b][cin][cout][tap] = dw[cout][tap]*proj_b[cout][cin] + center*W_a[cout][cin]
    for (int e = tid; e < CH * CH * 9; e += 256) {
        int cin = e / (CH * 9);
        int rem = e % (CH * 9);
        int o = rem / 9;
        int tap = rem % 9;
        float v = dw_b_w[o * 9 + tap] * proj_b_w[o * CH + cin];
        if (tap == 4) v += W_a[o * CH + cin];
        Wfx[b * (CH * CH * 9) + e] = v;
    }
}

// ---------------------------------------------------------------------------
// Kernel 2: repack expert weights [e][o][c][tap] -> [e][c][o][tap] so the
// expert kernel's inner loop reads contiguous uniform weights (s_load runs).
// ---------------------------------------------------------------------------
__global__ __launch_bounds__(256) void repack_kernel(
    const float* __restrict__ w1, const float* __restrict__ w2,
    float* __restrict__ w1r, float* __restrict__ w2r)
{
    int e = blockIdx.x;
    const float* src = blockIdx.y ? w2 : w1;
    float* dst = blockIdx.y ? w2r : w1r;
    for (int i = threadIdx.x; i < CH * CH * 9; i += 256) {
        int c = i / (CH * 9);
        int rem = i % (CH * 9);
        int o = rem / 9;
        int tap = rem % 9;
        dst[e * (CH * CH * 9) + i] = src[((e * CH + o) * CH + c) * 9 + tap];
    }
}

// ---------------------------------------------------------------------------
// Kernel 3: Fx = conv3x3(x, W_fx[b]), plus fused GAP partial sums.
// 16x16 pixel tile per block, one pixel per thread, 48 fp32 accumulators.
// x tile staged in LDS in 24-channel chunks (31.1 KB LDS).
// ---------------------------------------------------------------------------
#define K3_TILE 16
#define K3_CCHUNK 24
__global__ __launch_bounds__(256) void fx_kernel(
    const float* __restrict__ x,
    const float* __restrict__ Wfx,
    float* __restrict__ Fx,
    float* __restrict__ gap)
{
    int tx = blockIdx.x, ty = blockIdx.y, b = blockIdx.z;
    int tid = threadIdx.x;
    __shared__ float xt[K3_CCHUNK * 18 * 18];  // 31104 B

    int ox0 = tx * K3_TILE, oy0 = ty * K3_TILE;
    int px = tid & 15, py = tid >> 4;

    float acc[CH];
#pragma unroll
    for (int o = 0; o < CH; o++) acc[o] = 0.f;

    const float* wb = Wfx + b * (CH * CH * 9);

    for (int c0 = 0; c0 < CH; c0 += K3_CCHUNK) {
        __syncthreads();
        for (int i = tid; i < K3_CCHUNK * 324; i += 256) {
            int c = i / 324;
            int r = i % 324;
            int yy = r / 18, xx = r % 18;
            int gy = oy0 + yy - 1, gx = ox0 + xx - 1;
            float v = 0.f;
            if (gy >= 0 && gy < HH && gx >= 0 && gx < WW)
                v = x[((b * CH + (c0 + c)) * HH + gy) * WW + gx];
            xt[i] = v;
        }
        __syncthreads();

        for (int cl = 0; cl < K3_CCHUNK; cl++) {
            float xv[9];
#pragma unroll
            for (int dy = 0; dy < 3; dy++)
#pragma unroll
                for (int dx = 0; dx < 3; dx++)
                    xv[dy * 3 + dx] = xt[cl * 324 + (py + dy) * 18 + (px + dx)];
            const float* w = wb + ((c0 + cl) * CH) * 9;  // 432 contiguous uniform floats
#pragma unroll
            for (int o = 0; o < CH; o++) {
                float s = acc[o];
#pragma unroll
                for (int t = 0; t < 9; t++) s += w[o * 9 + t] * xv[t];
                acc[o] = s;
            }
        }
    }

    int gy = oy0 + py, gx = ox0 + px;
#pragma unroll
    for (int o = 0; o < CH; o++)
        Fx[((b * CH + o) * HH + gy) * WW + gx] = acc[o];

    // block-reduce each channel -> one atomicAdd per channel per block
    __syncthreads();
    float* red = xt;  // reuse (need 4*48 floats)
    int lane = tid & 63, wv = tid >> 6;
    for (int o = 0; o < CH; o++) {
        float v = acc[o];
        v += __shfl_down(v, 32);
        v += __shfl_down(v, 16);
        v += __shfl_down(v, 8);
        v += __shfl_down(v, 4);
        v += __shfl_down(v, 2);
        v += __shfl_down(v, 1);
        if (lane == 0) red[wv * CH + o] = v;
    }
    __syncthreads();
    if (tid < CH) {
        float s = red[tid] + red[CH + tid] + red[2 * CH + tid] + red[3 * CH + tid];
        atomicAdd(&gap[b * CH + tid], s);
    }
}

// ---------------------------------------------------------------------------
// Kernel 4: routing. gap sums -> mean -> scores -> top2 -> softmax gate.
// ---------------------------------------------------------------------------
__global__ void route_kernel(
    const float* __restrict__ gap,
    const float* __restrict__ router_w,
    const float* __restrict__ router_b,
    float* __restrict__ gate, int* __restrict__ eidx)
{
    int b = threadIdx.x;
    if (b >= BATCH) return;
    float sc[NEXP];
    for (int e = 0; e < NEXP; e++) {
        float s = router_b[e];
        for (int c = 0; c < CH; c++)
            s += (gap[b * CH + c] * (1.0f / HW)) * router_w[e * CH + c];
        sc[e] = s;
    }
    float v0 = -1e30f, v1 = -1e30f;
    int i0 = 0, i1 = 0;
    for (int e = 0; e < NEXP; e++) {
        if (sc[e] > v0) { v1 = v0; i1 = i0; v0 = sc[e]; i0 = e; }
        else if (sc[e] > v1) { v1 = sc[e]; i1 = e; }
    }
    float ex = expf(v1 - v0);
    float denom = 1.0f / (1.0f + ex);
    gate[b * 2 + 0] = denom;
    gate[b * 2 + 1] = ex * denom;
    eidx[b * 2 + 0] = i0;
    eidx[b * 2 + 1] = i1;
}

// ---------------------------------------------------------------------------
// Kernel 5: fused expert pass. For each 14x14 output tile:
//   load Fx (18x18x48, bf16 LDS), then for each of the 2 routed experts:
//   hmid = gelu(conv1) on 16x16 halo region (bf16 LDS), conv2 on 14x14,
//   accumulate gate-weighted. out = x + sum.
// LDS: 31104 + 24576 = 55680 B (2 blocks/CU).
// ---------------------------------------------------------------------------
#define K5_TILE 14
__global__ __launch_bounds__(256) void expert_kernel(
    const float* __restrict__ x,
    const float* __restrict__ Fx,
    const float* __restrict__ w1r,   // [e][cin][cout][9]
    const float* __restrict__ w2r,
    const float* __restrict__ gate,
    const int* __restrict__ eidx,
    float* __restrict__ out)
{
    int tx = blockIdx.x, ty = blockIdx.y, b = blockIdx.z;
    int tid = threadIdx.x;
    __shared__ __hip_bfloat16 fxt[CH * 18 * 18];  // 31104 B
    __shared__ __hip_bfloat16 hm[CH * 16 * 16];   // 24576 B

    int ox0 = tx * K5_TILE, oy0 = ty * K5_TILE;

    // Fx halo region: rows oy0-2 .. oy0+15
    for (int i = tid; i < CH * 324; i += 256) {
        int c = i / 324;
        int r = i % 324;
        int yy = r / 18, xx = r % 18;
        int gy = oy0 + yy - 2, gx = ox0 + xx - 2;
        float v = 0.f;
        if (gy >= 0 && gy < HH && gx >= 0 && gx < WW)
            v = Fx[((b * CH + c) * HH + gy) * WW + gx];
        fxt[i] = __float2bfloat16(v);
    }

    int hx = tid & 15, hy = tid >> 4;        // hmid pixel (16x16, 1/thread)
    int hgy = oy0 - 1 + hy, hgx = ox0 - 1 + hx;
    bool hvalid = (hgy >= 0 && hgy < HH && hgx >= 0 && hgx < WW);

    int py = tid / K5_TILE, px = tid % K5_TILE;  // output pixel (tid<196)

    float outacc[CH];
#pragma unroll
    for (int o = 0; o < CH; o++) outacc[o] = 0.f;

    for (int s = 0; s < 2; s++) {
        __syncthreads();  // fxt load done / hm free from previous slot
        int e = __builtin_amdgcn_readfirstlane(eidx[b * 2 + s]);
        float g = __uint_as_float(
            __builtin_amdgcn_readfirstlane(__float_as_uint(gate[b * 2 + s])));

        // ---- stage 1: hmid = gelu(conv1(Fx)) on 16x16 region ----
        {
            float acc[CH];
#pragma unroll
            for (int o = 0; o < CH; o++) acc[o] = 0.f;
            const float* wp = w1r + e * (CH * CH * 9);
            for (int c = 0; c < CH; c++) {
                float xv[9];
#pragma unroll
                for (int dy = 0; dy < 3; dy++)
#pragma unroll
                    for (int dx = 0; dx < 3; dx++)
                        xv[dy * 3 + dx] =
                            __bfloat162float(fxt[c * 324 + (hy + dy) * 18 + (hx + dx)]);
                const float* w = wp + (c * CH) * 9;
#pragma unroll
                for (int o = 0; o < CH; o++) {
                    float t = acc[o];
#pragma unroll
                    for (int k = 0; k < 9; k++) t += w[o * 9 + k] * xv[k];
                    acc[o] = t;
                }
            }
#pragma unroll
            for (int o = 0; o < CH; o++) {
                float a = acc[o];
                // exact gelu; positions outside the image must be 0 (the
                // reference zero-pads hmid, not gelu(conv(zero-pad)))
                float h = hvalid ? 0.5f * a * (1.0f + erff(a * 0.70710678118654752f))
                                 : 0.f;
                hm[o * 256 + hy * 16 + hx] = __float2bfloat16(h);
            }
        }
        __syncthreads();

        // ---- stage 2: e_out = conv2(hmid) on 14x14 outputs ----
        if (tid < K5_TILE * K5_TILE) {
            float acc[CH];
#pragma unroll
            for (int o = 0; o < CH; o++) acc[o] = 0.f;
            const float* wp = w2r + e * (CH * CH * 9);
            for (int c = 0; c < CH; c++) {
                float hv[9];
#pragma unroll
                for (int dy = 0; dy < 3; dy++)
#pragma unroll
                    for (int dx = 0; dx < 3; dx++)
                        hv[dy * 3 + dx] =
                            __bfloat162float(hm[c * 256 + (py + dy) * 16 + (px + dx)]);
                const float* w = wp + (c * CH) * 9;
#pragma unroll
                for (int o = 0; o < CH; o++) {
                    float t = acc[o];
#pragma unroll
                    for (int k = 0; k < 9; k++) t += w[o * 9 + k] * hv[k];
                    acc[o] = t;
                }
            }
#pragma unroll
            for (int o = 0; o < CH; o++) outacc[o] += g * acc[o];
        }
    }

    if (tid < K5_TILE * K5_TILE) {
        int gy = oy0 + py, gx = ox0 + px;
        if (gy < HH && gx < WW) {
#pragma unroll
            for (int o = 0; o < CH; o++) {
                int idx = ((b * CH + o) * HH + gy) * WW + gx;
                out[idx] = x[idx] + outacc[o];
            }
        }
    }
}

// ---------------------------------------------------------------------------
extern "C" void kernel_launch(void* const* d_in, const int* in_sizes, int n_in,
                              void* d_out, int out_size, void* d_ws, size_t ws_size,
                              hipStream_t stream) {
    (void)in_sizes; (void)n_in; (void)out_size; (void)ws_size;
    const float* x          = (const float*)d_in[0];
    const float* P_hat      = (const float*)d_in[1];
    const float* proj_a_w   = (const float*)d_in[2];
    const float* proj_b_w   = (const float*)d_in[3];
    const float* dw_b_w     = (const float*)d_in[4];
    const float* fi_align_w = (const float*)d_in[5];
    const float* expert_w1  = (const float*)d_in[6];
    const float* expert_w2  = (const float*)d_in[7];
    const float* router_w   = (const float*)d_in[8];
    const float* router_b   = (const float*)d_in[9];
    float* out = (float*)d_out;

    // workspace layout (floats)
    float* ws   = (float*)d_ws;
    float* Fx   = ws;                       // 25,165,824
    float* Wfx  = Fx + (size_t)BATCH * CH * HW;   // 165,888
    float* w1r  = Wfx + BATCH * CH * CH * 9;      // 331,776
    float* w2r  = w1r + NEXP * CH * CH * 9;       // 331,776
    float* gap  = w2r + NEXP * CH * CH * 9;       // 384
    float* gate = gap + BATCH * CH;               // 16
    int*   eidx = (int*)(gate + BATCH * 2);       // 16

    precompute_kernel<<<dim3(BATCH), 256, 0, stream>>>(
        P_hat, proj_a_w, proj_b_w, dw_b_w, fi_align_w, Wfx, gap);

    repack_kernel<<<dim3(NEXP, 2), 256, 0, stream>>>(
        expert_w1, expert_w2, w1r, w2r);

    fx_kernel<<<dim3(WW / K3_TILE, HH / K3_TILE, BATCH), 256, 0, stream>>>(
        x, Wfx, Fx, gap);

    route_kernel<<<dim3(1), 64, 0, stream>>>(gap, router_w, router_b, gate, eidx);

    int nt = (HH + K5_TILE - 1) / K5_TILE;  // 19
    expert_kernel<<<dim3(nt, nt, BATCH), 256, 0, stream>>>(
        x, Fx, w1r, w2r, gate, eidx, out);
}

// Round 2
// 1044.535 us; speedup vs baseline: 5.2107x; 5.2107x over previous
//
#include <hip/hip_runtime.h>
#include <hip/hip_bf16.h>
#include <math.h>

#define BATCH 8
#define CH 48
#define HH 256
#define WW 256
#define NPROMPT 16
#define NEXP 8
#define NGRP 4
#define GDIM 12
#define HW (HH * WW)

// MFMA fragment tables: [tap(9)][mtile(3)][kblock(2)][lane(64)][j(8)] bf16
// value = W[oc = mt*16 + (lane&15)][cin = kb*32 + (lane>>4)*8 + j][tap], 0 for cin>=48
#define FRAG_ELEMS (9 * 3 * 2 * 64 * 8)   // 27648 per (image|expert)

typedef int   i32x4 __attribute__((ext_vector_type(4)));   // 8 bf16
typedef float f32x4 __attribute__((ext_vector_type(4)));

#define TILE 16
#define ITILE 18
#define NPIX (ITILE * ITILE)      // 324
#define PIXB 144                  // 64 cin * 2B + 16 pad (bank-friendly stride)
#define LDSBYTES (NPIX * PIXB)    // 46656

__device__ __forceinline__ void mfma16(f32x4& d, i32x4 a, i32x4 b) {
    asm("v_mfma_f32_16x16x32_bf16 %0, %1, %2, %0" : "+v"(d) : "v"(a), "v"(b));
}
__device__ __forceinline__ void acc_fence(f32x4& d) {
    // MFMA-write -> VALU-read hazard cover (compiler can't see through asm)
    asm volatile("s_nop 7\ns_nop 7\ns_nop 3" : "+v"(d));
}

// ---------------------------------------------------------------------------
// Kernel 1: fold branch-a (prompt 1x1 + fi_align) + branch-b (1x1 + dw3x3)
// into per-image 3x3 weights, emitted directly in MFMA A-fragment layout.
// ---------------------------------------------------------------------------
__global__ __launch_bounds__(256) void precompute_kernel(
    const float* __restrict__ P_hat,
    const float* __restrict__ proj_a_w,
    const float* __restrict__ proj_b_w,
    const float* __restrict__ dw_b_w,
    const float* __restrict__ fi_align_w,
    __hip_bfloat16* __restrict__ wfxf,
    float* __restrict__ gap)
{
    int b = blockIdx.x;
    int tid = threadIdx.x;
    __shared__ float p_avg[CH];
    __shared__ float W_fi[NGRP * CH];
    __shared__ float W_a[CH * CH];

    if (tid < CH) {
        float s = 0.f;
        for (int n = 0; n < NPROMPT; n++)
            s += P_hat[(b * NPROMPT + n) * CH + tid];
        p_avg[tid] = s * (1.0f / NPROMPT);
    }
    if (b == 0) {
        for (int i = tid; i < BATCH * CH; i += 256) gap[i] = 0.f;
    }
    __syncthreads();

    if (tid < NGRP * CH) {
        int g = tid / CH, k = tid % CH;
        float s = 0.f;
        for (int j = 0; j < GDIM; j++) {
            int c = g * GDIM + j;
            s += p_avg[c] * proj_a_w[c * CH + k];
        }
        W_fi[tid] = s;
    }
    __syncthreads();

    for (int e = tid; e < CH * CH; e += 256) {
        int o = e / CH, k = e % CH;
        float s = 0.f;
        for (int g = 0; g < NGRP; g++)
            s += fi_align_w[o * NGRP + g] * W_fi[g * CH + k];
        W_a[e] = s;
    }
    __syncthreads();

    for (int i = tid; i < FRAG_ELEMS; i += 256) {
        int j = i & 7;
        int lane = (i >> 3) & 63;
        int blk = i >> 9;            // (tap*3+mt)*2+kb
        int kb = blk & 1;
        int tmp = blk >> 1;
        int mt = tmp % 3, tap = tmp / 3;
        int oc = mt * 16 + (lane & 15);
        int cin = kb * 32 + (lane >> 4) * 8 + j;
        float v = 0.f;
        if (cin < CH) {
            v = dw_b_w[oc * 9 + tap] * proj_b_w[oc * CH + cin];
            if (tap == 4) v += W_a[oc * CH + cin];
        }
        wfxf[(size_t)b * FRAG_ELEMS + i] = __float2bfloat16(v);
    }
}

// ---------------------------------------------------------------------------
// Kernel 2: repack expert weights into MFMA A-fragment layout (bf16).
// ---------------------------------------------------------------------------
__global__ __launch_bounds__(256) void repack_kernel(
    const float* __restrict__ w1, const float* __restrict__ w2,
    __hip_bfloat16* __restrict__ w1f, __hip_bfloat16* __restrict__ w2f)
{
    int e = blockIdx.x;
    const float* src = blockIdx.y ? w2 : w1;
    __hip_bfloat16* dst = blockIdx.y ? w2f : w1f;
    for (int i = threadIdx.x; i < FRAG_ELEMS; i += 256) {
        int j = i & 7;
        int lane = (i >> 3) & 63;
        int blk = i >> 9;
        int kb = blk & 1;
        int tmp = blk >> 1;
        int mt = tmp % 3, tap = tmp / 3;
        int oc = mt * 16 + (lane & 15);
        int cin = kb * 32 + (lane >> 4) * 8 + j;
        float v = (cin < CH) ? src[(((size_t)e * CH + oc) * CH + cin) * 9 + tap] : 0.f;
        dst[(size_t)e * FRAG_ELEMS + i] = __float2bfloat16(v);
    }
}

// ---------------------------------------------------------------------------
// Shared conv machinery: stage 18x18x48 tile (zero-padded to cin=64) into LDS
// as [pixel][cin] bf16, then 9-tap x (K=64) MFMA GEMM, M=48, N=16/row-group.
// ---------------------------------------------------------------------------
template <typename T>
__device__ __forceinline__ void stage_tile(const T* __restrict__ in, int z,
                                           int oy0, int ox0, char* smem)
{
    for (int i = threadIdx.x; i < CH * NPIX; i += 256) {
        int c = i / NPIX;
        int p = i - c * NPIX;
        int yy = p / ITILE, xx = p - yy * ITILE;
        int gy = oy0 + yy - 1, gx = ox0 + xx - 1;
        float v = 0.f;
        if ((unsigned)gy < 256u && (unsigned)gx < 256u)
            v = (float)in[(((size_t)z * CH + c) << 16) + (gy << 8) + gx];
        *(__hip_bfloat16*)(smem + p * PIXB + c * 2) = __float2bfloat16(v);
    }
    // zero cin 48..63 pad (also used as the acc zero-init source)
    for (int i = threadIdx.x; i < NPIX * 4; i += 256) {
        int p = i >> 2, q = i & 3;
        *(unsigned long long*)(smem + p * PIXB + 96 + q * 8) = 0ull;
    }
}

__device__ __forceinline__ void conv3x3_core(
    const char* smem, const __hip_bfloat16* __restrict__ wfrag, f32x4 acc[4][3])
{
    const int lane = threadIdx.x & 63;
    const int wv = threadIdx.x >> 6;
    const int n = lane & 15;
    const int quad = lane >> 4;
    const i32x4* wp = (const i32x4*)wfrag;

    // acc zero-init by ds_read of known-zero pad bytes: keeps the first MFMA's
    // SrcC behind an lgkmcnt wait instead of a VALU write (hazard-safe).
#pragma unroll
    for (int g = 0; g < 4; ++g)
#pragma unroll
        for (int mt = 0; mt < 3; ++mt)
            acc[g][mt] = *(const f32x4*)(smem + (g * 3 + mt) * PIXB + 96);

#pragma unroll
    for (int tap = 0; tap < 9; ++tap) {
        const int dy = tap / 3, dx = tap % 3;
        i32x4 a0  = wp[((tap * 3 + 0) * 2 + 0) * 64 + lane];
        i32x4 a1  = wp[((tap * 3 + 1) * 2 + 0) * 64 + lane];
        i32x4 a2  = wp[((tap * 3 + 2) * 2 + 0) * 64 + lane];
        i32x4 a0b = wp[((tap * 3 + 0) * 2 + 1) * 64 + lane];
        i32x4 a1b = wp[((tap * 3 + 1) * 2 + 1) * 64 + lane];
        i32x4 a2b = wp[((tap * 3 + 2) * 2 + 1) * 64 + lane];
#pragma unroll
        for (int g = 0; g < 4; ++g) {
            const int base = ((wv * 4 + g + dy) * ITILE + dx + n) * PIXB;
            i32x4 b0 = *(const i32x4*)(smem + base + quad * 16);
            i32x4 b1 = *(const i32x4*)(smem + base + 64 + quad * 16);
            mfma16(acc[g][0], a0, b0);
            mfma16(acc[g][1], a1, b0);
            mfma16(acc[g][2], a2, b0);
            mfma16(acc[g][0], a0b, b1);
            mfma16(acc[g][1], a1b, b1);
            mfma16(acc[g][2], a2b, b1);
        }
    }
#pragma unroll
    for (int g = 0; g < 4; ++g)
#pragma unroll
        for (int mt = 0; mt < 3; ++mt)
            acc_fence(acc[g][mt]);
}

// ---------------------------------------------------------------------------
// Kernel 3: Fx conv (x fp32 in, per-image folded weights) + fused GAP.
// ---------------------------------------------------------------------------
__global__ __launch_bounds__(256, 3) void fxconv_kernel(
    const float* __restrict__ x, const __hip_bfloat16* __restrict__ wfxf,
    __hip_bfloat16* __restrict__ Fx, float* __restrict__ gap)
{
    __shared__ __align__(16) char smem[LDSBYTES];
    int ox0 = blockIdx.x * TILE, oy0 = blockIdx.y * TILE, b = blockIdx.z;
    stage_tile(x, b, oy0, ox0, smem);
    __syncthreads();

    f32x4 acc[4][3];
    conv3x3_core(smem, wfxf + (size_t)b * FRAG_ELEMS, acc);

    const int lane = threadIdx.x & 63;
    const int wv = threadIdx.x >> 6;
    const int n = lane & 15, quad = lane >> 4;

    float gsum[3][4];
#pragma unroll
    for (int mt = 0; mt < 3; ++mt)
#pragma unroll
        for (int r = 0; r < 4; ++r) gsum[mt][r] = 0.f;

#pragma unroll
    for (int g = 0; g < 4; ++g) {
        int row = oy0 + wv * 4 + g;
#pragma unroll
        for (int mt = 0; mt < 3; ++mt)
#pragma unroll
            for (int r = 0; r < 4; ++r) {
                float v = acc[g][mt][r];
                int oc = mt * 16 + quad * 4 + r;
                Fx[(((size_t)b * CH + oc) << 16) + (row << 8) + ox0 + n] =
                    __float2bfloat16(v);
                gsum[mt][r] += v;
            }
    }
#pragma unroll
    for (int mt = 0; mt < 3; ++mt)
#pragma unroll
        for (int r = 0; r < 4; ++r) {
            float v = gsum[mt][r];
            v += __shfl_xor(v, 1);
            v += __shfl_xor(v, 2);
            v += __shfl_xor(v, 4);
            v += __shfl_xor(v, 8);
            if (n == 0)
                atomicAdd(&gap[b * CH + mt * 16 + quad * 4 + r], v);
        }
}

// ---------------------------------------------------------------------------
// Kernel 4: routing (gap -> scores -> top2 softmax gate).
// ---------------------------------------------------------------------------
__global__ void route_kernel(
    const float* __restrict__ gap,
    const float* __restrict__ router_w,
    const float* __restrict__ router_b,
    float* __restrict__ gate, int* __restrict__ eidx)
{
    int b = threadIdx.x;
    if (b >= BATCH) return;
    float sc[NEXP];
    for (int e = 0; e < NEXP; e++) {
        float s = router_b[e];
        for (int c = 0; c < CH; c++)
            s += (gap[b * CH + c] * (1.0f / HW)) * router_w[e * CH + c];
        sc[e] = s;
    }
    float v0 = -1e30f, v1 = -1e30f;
    int i0 = 0, i1 = 0;
    for (int e = 0; e < NEXP; e++) {
        if (sc[e] > v0) { v1 = v0; i1 = i0; v0 = sc[e]; i0 = e; }
        else if (sc[e] > v1) { v1 = sc[e]; i1 = e; }
    }
    float ex = expf(v1 - v0);
    float denom = 1.0f / (1.0f + ex);
    gate[b * 2 + 0] = denom;
    gate[b * 2 + 1] = ex * denom;
    eidx[b * 2 + 0] = i0;
    eidx[b * 2 + 1] = i1;
}

// ---------------------------------------------------------------------------
// Kernel 5: conv1 for one routed slot: hmid = gelu(conv3x3(Fx, w1[e])).
// ---------------------------------------------------------------------------
__global__ __launch_bounds__(256, 3) void conv1_kernel(
    const __hip_bfloat16* __restrict__ Fx, const __hip_bfloat16* __restrict__ w1f,
    const int* __restrict__ eidx, int slot, __hip_bfloat16* __restrict__ hmid)
{
    __shared__ __align__(16) char smem[LDSBYTES];
    int ox0 = blockIdx.x * TILE, oy0 = blockIdx.y * TILE, b = blockIdx.z;
    int e = __builtin_amdgcn_readfirstlane(eidx[b * 2 + slot]);

    stage_tile(Fx, b, oy0, ox0, smem);
    __syncthreads();

    f32x4 acc[4][3];
    conv3x3_core(smem, w1f + (size_t)e * FRAG_ELEMS, acc);

    const int lane = threadIdx.x & 63;
    const int wv = threadIdx.x >> 6;
    const int n = lane & 15, quad = lane >> 4;
#pragma unroll
    for (int g = 0; g < 4; ++g) {
        int row = oy0 + wv * 4 + g;
#pragma unroll
        for (int mt = 0; mt < 3; ++mt)
#pragma unroll
            for (int r = 0; r < 4; ++r) {
                float a = acc[g][mt][r];
                float h = 0.5f * a * (1.0f + erff(a * 0.70710678118654752f));
                int oc = mt * 16 + quad * 4 + r;
                hmid[(((size_t)b * CH + oc) << 16) + (row << 8) + ox0 + n] =
                    __float2bfloat16(h);
            }
    }
}

// ---------------------------------------------------------------------------
// Kernel 6: conv2 for one routed slot: out = addin + gate * conv3x3(hmid, w2[e]).
// slot0: addin = x; slot1: addin = out (stream-ordered accumulate).
// ---------------------------------------------------------------------------
__global__ __launch_bounds__(256, 3) void conv2_kernel(
    const __hip_bfloat16* __restrict__ hmid, const __hip_bfloat16* __restrict__ w2f,
    const int* __restrict__ eidx, const float* __restrict__ gate, int slot,
    const float* __restrict__ addin, float* __restrict__ out)
{
    __shared__ __align__(16) char smem[LDSBYTES];
    int ox0 = blockIdx.x * TILE, oy0 = blockIdx.y * TILE, b = blockIdx.z;
    int e = __builtin_amdgcn_readfirstlane(eidx[b * 2 + slot]);
    float gv = __uint_as_float(
        __builtin_amdgcn_readfirstlane(__float_as_uint(gate[b * 2 + slot])));

    stage_tile(hmid, b, oy0, ox0, smem);
    __syncthreads();

    f32x4 acc[4][3];
    conv3x3_core(smem, w2f + (size_t)e * FRAG_ELEMS, acc);

    const int lane = threadIdx.x & 63;
    const int wv = threadIdx.x >> 6;
    const int n = lane & 15, quad = lane >> 4;
#pragma unroll
    for (int g = 0; g < 4; ++g) {
        int row = oy0 + wv * 4 + g;
#pragma unroll
        for (int mt = 0; mt < 3; ++mt)
#pragma unroll
            for (int r = 0; r < 4; ++r) {
                int oc = mt * 16 + quad * 4 + r;
                size_t idx = (((size_t)b * CH + oc) << 16) + (row << 8) + ox0 + n;
                out[idx] = addin[idx] + gv * acc[g][mt][r];
            }
    }
}

// ---------------------------------------------------------------------------
extern "C" void kernel_launch(void* const* d_in, const int* in_sizes, int n_in,
                              void* d_out, int out_size, void* d_ws, size_t ws_size,
                              hipStream_t stream) {
    (void)in_sizes; (void)n_in; (void)out_size; (void)ws_size;
    const float* x          = (const float*)d_in[0];
    const float* P_hat      = (const float*)d_in[1];
    const float* proj_a_w   = (const float*)d_in[2];
    const float* proj_b_w   = (const float*)d_in[3];
    const float* dw_b_w     = (const float*)d_in[4];
    const float* fi_align_w = (const float*)d_in[5];
    const float* expert_w1  = (const float*)d_in[6];
    const float* expert_w2  = (const float*)d_in[7];
    const float* router_w   = (const float*)d_in[8];
    const float* router_b   = (const float*)d_in[9];
    float* out = (float*)d_out;

    char* ws = (char*)d_ws;
    __hip_bfloat16* Fx   = (__hip_bfloat16*)ws;                       // 50,331,648 B
    __hip_bfloat16* hmid = (__hip_bfloat16*)(ws + 50331648);          // 50,331,648 B
    __hip_bfloat16* wfxf = (__hip_bfloat16*)(ws + 100663296);         // 442,368 B
    __hip_bfloat16* w1f  = (__hip_bfloat16*)(ws + 100663296 + 442368);
    __hip_bfloat16* w2f  = (__hip_bfloat16*)(ws + 100663296 + 2 * 442368);
    float* gap  = (float*)(ws + 100663296 + 3 * 442368);              // 1536 B
    float* gate = gap + BATCH * CH;
    int*   eidx = (int*)(gate + BATCH * 2);

    precompute_kernel<<<dim3(BATCH), 256, 0, stream>>>(
        P_hat, proj_a_w, proj_b_w, dw_b_w, fi_align_w, wfxf, gap);

    repack_kernel<<<dim3(NEXP, 2), 256, 0, stream>>>(
        expert_w1, expert_w2, w1f, w2f);

    fxconv_kernel<<<dim3(16, 16, BATCH), 256, 0, stream>>>(x, wfxf, Fx, gap);

    route_kernel<<<dim3(1), 64, 0, stream>>>(gap, router_w, router_b, gate, eidx);

    conv1_kernel<<<dim3(16, 16, BATCH), 256, 0, stream>>>(Fx, w1f, eidx, 0, hmid);
    conv2_kernel<<<dim3(16, 16, BATCH), 256, 0, stream>>>(hmid, w2f, eidx, gate, 0, x, out);
    conv1_kernel<<<dim3(16, 16, BATCH), 256, 0, stream>>>(Fx, w1f, eidx, 1, hmid);
    conv2_kernel<<<dim3(16, 16, BATCH), 256, 0, stream>>>(hmid, w2f, eidx, gate, 1, out, out);
}

// Round 3
// 804.614 us; speedup vs baseline: 6.7644x; 1.2982x over previous
//
#include <hip/hip_runtime.h>
#include <hip/hip_bf16.h>
#include <math.h>

#define BATCH 8
#define CH 48
#define HH 256
#define WW 256
#define NPROMPT 16
#define NEXP 8
#define NGRP 4
#define GDIM 12
#define HW (HH * WW)

// MFMA fragment tables: [tap(9)][mtile(3)][kblock(2)][lane(64)][j(8)] bf16
// value = W[oc = mt*16 + (lane&15)][cin = kb*32 + (lane>>4)*8 + j][tap], 0 for cin>=48
#define FRAG_ELEMS (9 * 3 * 2 * 64 * 8)   // 27648 per (image|expert)

typedef short bf16x8 __attribute__((ext_vector_type(8)));   // 8 bf16 (4 VGPRs)
typedef int   i32x4  __attribute__((ext_vector_type(4)));
typedef float f32x4  __attribute__((ext_vector_type(4)));
typedef unsigned short u16x4 __attribute__((ext_vector_type(4)));

#define TILE 16
#define ITILE 18
#define NPIX (ITILE * ITILE)      // 324
#define PIXB 144                  // 64 cin * 2B + 16 pad
#define LDSBYTES (NPIX * PIXB)    // 46656
#define NITEM (NPIX * 6)          // 1944 staging octet-items

__device__ __forceinline__ unsigned short f2bf(float f) {
    unsigned u = __float_as_uint(f);
    unsigned r = (u + 0x7FFFu + ((u >> 16) & 1u)) >> 16;   // RNE
    return (unsigned short)r;
}

// ---------------------------------------------------------------------------
// Kernel 1: fold branch-a + branch-b into per-image 3x3 weights in MFMA
// A-fragment layout. Also zero the gap accumulator.
// ---------------------------------------------------------------------------
__global__ __launch_bounds__(256) void precompute_kernel(
    const float* __restrict__ P_hat,
    const float* __restrict__ proj_a_w,
    const float* __restrict__ proj_b_w,
    const float* __restrict__ dw_b_w,
    const float* __restrict__ fi_align_w,
    unsigned short* __restrict__ wfxf,
    float* __restrict__ gap)
{
    int b = blockIdx.x;
    int tid = threadIdx.x;
    __shared__ float p_avg[CH];
    __shared__ float W_fi[NGRP * CH];
    __shared__ float W_a[CH * CH];

    if (tid < CH) {
        float s = 0.f;
        for (int n = 0; n < NPROMPT; n++)
            s += P_hat[(b * NPROMPT + n) * CH + tid];
        p_avg[tid] = s * (1.0f / NPROMPT);
    }
    if (b == 0) {
        for (int i = tid; i < BATCH * CH; i += 256) gap[i] = 0.f;
    }
    __syncthreads();

    if (tid < NGRP * CH) {
        int g = tid / CH, k = tid % CH;
        float s = 0.f;
        for (int j = 0; j < GDIM; j++) {
            int c = g * GDIM + j;
            s += p_avg[c] * proj_a_w[c * CH + k];
        }
        W_fi[tid] = s;
    }
    __syncthreads();

    for (int e = tid; e < CH * CH; e += 256) {
        int o = e / CH, k = e % CH;
        float s = 0.f;
        for (int g = 0; g < NGRP; g++)
            s += fi_align_w[o * NGRP + g] * W_fi[g * CH + k];
        W_a[e] = s;
    }
    __syncthreads();

    for (int i = tid; i < FRAG_ELEMS; i += 256) {
        int j = i & 7;
        int lane = (i >> 3) & 63;
        int blk = i >> 9;            // (tap*3+mt)*2+kb
        int kb = blk & 1;
        int tmp = blk >> 1;
        int mt = tmp % 3, tap = tmp / 3;
        int oc = mt * 16 + (lane & 15);
        int cin = kb * 32 + (lane >> 4) * 8 + j;
        float v = 0.f;
        if (cin < CH) {
            v = dw_b_w[oc * 9 + tap] * proj_b_w[oc * CH + cin];
            if (tap == 4) v += W_a[oc * CH + cin];
        }
        wfxf[(size_t)b * FRAG_ELEMS + i] = f2bf(v);
    }
}

// ---------------------------------------------------------------------------
// Kernel 2: repack expert weights into MFMA A-fragment layout.
// ---------------------------------------------------------------------------
__global__ __launch_bounds__(256) void repack_kernel(
    const float* __restrict__ w1, const float* __restrict__ w2,
    unsigned short* __restrict__ w1f, unsigned short* __restrict__ w2f)
{
    int e = blockIdx.x;
    const float* src = blockIdx.y ? w2 : w1;
    unsigned short* dst = blockIdx.y ? w2f : w1f;
    for (int i = threadIdx.x; i < FRAG_ELEMS; i += 256) {
        int j = i & 7;
        int lane = (i >> 3) & 63;
        int blk = i >> 9;
        int kb = blk & 1;
        int tmp = blk >> 1;
        int mt = tmp % 3, tap = tmp / 3;
        int oc = mt * 16 + (lane & 15);
        int cin = kb * 32 + (lane >> 4) * 8 + j;
        float v = (cin < CH) ? src[(((size_t)e * CH + oc) * CH + cin) * 9 + tap] : 0.f;
        dst[(size_t)e * FRAG_ELEMS + i] = f2bf(v);
    }
}

// ---------------------------------------------------------------------------
// Staging: fill LDS tile [pixel 18x18][cin 0..63 (48..63 zero)] bf16.
// ---------------------------------------------------------------------------
__device__ __forceinline__ void zero_pad(char* smem) {
    for (int i = threadIdx.x; i < NPIX * 3; i += 256) {
        int p = i / 3, q = i % 3;
        *(i32x4*)(smem + p * PIXB + 96 + q * 16) = (i32x4){0, 0, 0, 0};
    }
}

// from NCHW fp32 (x input): 8 independent scalar loads per octet, 4 octets
// in flight between waitcnts.
__device__ __forceinline__ void stage_nchw_f32(
    const float* __restrict__ in, int b, int oy0, int ox0, char* smem)
{
    zero_pad(smem);
    int t = threadIdx.x;
#pragma unroll
    for (int half = 0; half < 2; ++half) {
        float v[4][8];
        int pp[4], oo[4];
        bool act[4];
#pragma unroll
        for (int k = 0; k < 4; ++k) {
            int w = t + 256 * (half * 4 + k);
            act[k] = (w < NITEM);
            int p = w / 6, o = w - p * 6;
            pp[k] = p; oo[k] = o;
            int yy = p / ITILE, xx = p - yy * ITILE;
            int gy = oy0 + yy - 1, gx = ox0 + xx - 1;
            bool valid = act[k] && ((unsigned)gy < 256u) && ((unsigned)gx < 256u);
            const float* base = in + (((size_t)(b * CH + o * 8)) << 16) + (gy << 8) + gx;
#pragma unroll
            for (int j = 0; j < 8; ++j) {
                float xv = 0.f;
                if (valid) xv = base[(size_t)j << 16];
                v[k][j] = xv;
            }
        }
#pragma unroll
        for (int k = 0; k < 4; ++k) {
            if (act[k]) {
                bf16x8 pk;
#pragma unroll
                for (int j = 0; j < 8; ++j) pk[j] = (short)f2bf(v[k][j]);
                *(bf16x8*)(smem + pp[k] * PIXB + oo[k] * 16) = pk;
            }
        }
    }
}

// from NHWC bf16 (Fx/hmid): one int4 load per octet.
__device__ __forceinline__ void stage_nhwc_bf16(
    const unsigned short* __restrict__ in, int b, int oy0, int ox0, char* smem)
{
    zero_pad(smem);
    int t = threadIdx.x;
    const char* inb = (const char*)in;
#pragma unroll
    for (int half = 0; half < 2; ++half) {
        i32x4 v[4];
        int pp[4], oo[4];
        bool act[4];
#pragma unroll
        for (int k = 0; k < 4; ++k) {
            int w = t + 256 * (half * 4 + k);
            act[k] = (w < NITEM);
            int p = w / 6, o = w - p * 6;
            pp[k] = p; oo[k] = o;
            int yy = p / ITILE, xx = p - yy * ITILE;
            int gy = oy0 + yy - 1, gx = ox0 + xx - 1;
            bool valid = act[k] && ((unsigned)gy < 256u) && ((unsigned)gx < 256u);
            i32x4 xv = {0, 0, 0, 0};
            if (valid)
                xv = *(const i32x4*)(inb + (size_t)((b << 16) + (gy << 8) + gx) * 96 + o * 16);
            v[k] = xv;
        }
#pragma unroll
        for (int k = 0; k < 4; ++k)
            if (act[k]) *(i32x4*)(smem + pp[k] * PIXB + oo[k] * 16) = v[k];
    }
}

// ---------------------------------------------------------------------------
// Core: 9-tap K=64 MFMA GEMM. M=48 (3 mtiles), N=16 px/row, 4 rows per wave.
// A-frags double-buffered across taps.
// ---------------------------------------------------------------------------
__device__ __forceinline__ void conv_core(
    const char* smem, const unsigned short* __restrict__ wfrag, f32x4 acc[4][3])
{
    const int lane = threadIdx.x & 63;
    const int wv = threadIdx.x >> 6;
    const int n = lane & 15;
    const int quad = lane >> 4;
    const bf16x8* wp = (const bf16x8*)wfrag;

#pragma unroll
    for (int g = 0; g < 4; ++g)
#pragma unroll
        for (int mt = 0; mt < 3; ++mt)
            acc[g][mt] = (f32x4){0.f, 0.f, 0.f, 0.f};

    // A-frag buffer order: [mt0 kb0, mt1 kb0, mt2 kb0, mt0 kb1, mt1 kb1, mt2 kb1]
    bf16x8 a[2][6];
#pragma unroll
    for (int mt = 0; mt < 3; ++mt) {
        a[0][mt]     = wp[(mt * 2 + 0) * 64 + lane];
        a[0][mt + 3] = wp[(mt * 2 + 1) * 64 + lane];
    }

#pragma unroll
    for (int tap = 0; tap < 9; ++tap) {
        const int cur = tap & 1;
        if (tap < 8) {
#pragma unroll
            for (int mt = 0; mt < 3; ++mt) {
                a[cur ^ 1][mt]     = wp[(((tap + 1) * 3 + mt) * 2 + 0) * 64 + lane];
                a[cur ^ 1][mt + 3] = wp[(((tap + 1) * 3 + mt) * 2 + 1) * 64 + lane];
            }
        }
        const int dy = tap / 3, dx = tap % 3;
#pragma unroll
        for (int g = 0; g < 4; ++g) {
            const int base = ((wv * 4 + g + dy) * ITILE + dx + n) * PIXB;
            bf16x8 b0 = *(const bf16x8*)(smem + base + quad * 16);
            bf16x8 b1 = *(const bf16x8*)(smem + base + 64 + quad * 16);
            acc[g][0] = __builtin_amdgcn_mfma_f32_16x16x32_bf16(a[cur][0], b0, acc[g][0], 0, 0, 0);
            acc[g][1] = __builtin_amdgcn_mfma_f32_16x16x32_bf16(a[cur][1], b0, acc[g][1], 0, 0, 0);
            acc[g][2] = __builtin_amdgcn_mfma_f32_16x16x32_bf16(a[cur][2], b0, acc[g][2], 0, 0, 0);
            acc[g][0] = __builtin_amdgcn_mfma_f32_16x16x32_bf16(a[cur][3], b1, acc[g][0], 0, 0, 0);
            acc[g][1] = __builtin_amdgcn_mfma_f32_16x16x32_bf16(a[cur][4], b1, acc[g][1], 0, 0, 0);
            acc[g][2] = __builtin_amdgcn_mfma_f32_16x16x32_bf16(a[cur][5], b1, acc[g][2], 0, 0, 0);
        }
    }
}

// ---------------------------------------------------------------------------
// Kernel 3: Fx = conv3x3(x, Wfx[b])  (NCHW fp32 -> NHWC bf16) + fused GAP.
// ---------------------------------------------------------------------------
__global__ __launch_bounds__(256, 3) void fxconv_kernel(
    const float* __restrict__ x, const unsigned short* __restrict__ wfxf,
    unsigned short* __restrict__ Fx, float* __restrict__ gap)
{
    __shared__ __align__(16) char smem[LDSBYTES];
    int ox0 = blockIdx.x * TILE, oy0 = blockIdx.y * TILE, b = blockIdx.z;
    stage_nchw_f32(x, b, oy0, ox0, smem);
    __syncthreads();

    f32x4 acc[4][3];
    conv_core(smem, wfxf + (size_t)b * FRAG_ELEMS, acc);

    const int lane = threadIdx.x & 63;
    const int wv = threadIdx.x >> 6;
    const int n = lane & 15, quad = lane >> 4;

    float gsum[3][4];
#pragma unroll
    for (int mt = 0; mt < 3; ++mt)
#pragma unroll
        for (int r = 0; r < 4; ++r) gsum[mt][r] = 0.f;

#pragma unroll
    for (int g = 0; g < 4; ++g) {
        int row = oy0 + wv * 4 + g;
        unsigned short* pix = Fx + (size_t)((b << 16) + (row << 8) + ox0 + n) * CH;
#pragma unroll
        for (int mt = 0; mt < 3; ++mt) {
            u16x4 pk;
#pragma unroll
            for (int r = 0; r < 4; ++r) {
                float v = acc[g][mt][r];
                pk[r] = f2bf(v);
                gsum[mt][r] += v;
            }
            *(u16x4*)(pix + mt * 16 + quad * 4) = pk;
        }
    }
#pragma unroll
    for (int mt = 0; mt < 3; ++mt)
#pragma unroll
        for (int r = 0; r < 4; ++r) {
            float v = gsum[mt][r];
            v += __shfl_xor(v, 1);
            v += __shfl_xor(v, 2);
            v += __shfl_xor(v, 4);
            v += __shfl_xor(v, 8);
            if (n == 0)
                atomicAdd(&gap[b * CH + mt * 16 + quad * 4 + r], v);
        }
}

// ---------------------------------------------------------------------------
// Kernel 4: routing.
// ---------------------------------------------------------------------------
__global__ void route_kernel(
    const float* __restrict__ gap,
    const float* __restrict__ router_w,
    const float* __restrict__ router_b,
    float* __restrict__ gate, int* __restrict__ eidx)
{
    int b = threadIdx.x;
    if (b >= BATCH) return;
    float sc[NEXP];
    for (int e = 0; e < NEXP; e++) {
        float s = router_b[e];
        for (int c = 0; c < CH; c++)
            s += (gap[b * CH + c] * (1.0f / HW)) * router_w[e * CH + c];
        sc[e] = s;
    }
    float v0 = -1e30f, v1 = -1e30f;
    int i0 = 0, i1 = 0;
    for (int e = 0; e < NEXP; e++) {
        if (sc[e] > v0) { v1 = v0; i1 = i0; v0 = sc[e]; i0 = e; }
        else if (sc[e] > v1) { v1 = sc[e]; i1 = e; }
    }
    float ex = expf(v1 - v0);
    float denom = 1.0f / (1.0f + ex);
    gate[b * 2 + 0] = denom;
    gate[b * 2 + 1] = ex * denom;
    eidx[b * 2 + 0] = i0;
    eidx[b * 2 + 1] = i1;
}

// ---------------------------------------------------------------------------
// Kernel 5: hmid = gelu(conv3x3(Fx, w1[e]))  (NHWC bf16 -> NHWC bf16).
// ---------------------------------------------------------------------------
__global__ __launch_bounds__(256, 3) void conv1_kernel(
    const unsigned short* __restrict__ Fx, const unsigned short* __restrict__ w1f,
    const int* __restrict__ eidx, int slot, unsigned short* __restrict__ hmid)
{
    __shared__ __align__(16) char smem[LDSBYTES];
    int ox0 = blockIdx.x * TILE, oy0 = blockIdx.y * TILE, b = blockIdx.z;
    int e = __builtin_amdgcn_readfirstlane(eidx[b * 2 + slot]);

    stage_nhwc_bf16(Fx, b, oy0, ox0, smem);
    __syncthreads();

    f32x4 acc[4][3];
    conv_core(smem, w1f + (size_t)e * FRAG_ELEMS, acc);

    const int lane = threadIdx.x & 63;
    const int wv = threadIdx.x >> 6;
    const int n = lane & 15, quad = lane >> 4;
#pragma unroll
    for (int g = 0; g < 4; ++g) {
        int row = oy0 + wv * 4 + g;
        unsigned short* pix = hmid + (size_t)((b << 16) + (row << 8) + ox0 + n) * CH;
#pragma unroll
        for (int mt = 0; mt < 3; ++mt) {
            u16x4 pk;
#pragma unroll
            for (int r = 0; r < 4; ++r) {
                float a = acc[g][mt][r];
                float h = 0.5f * a * (1.0f + erff(a * 0.70710678118654752f));
                pk[r] = f2bf(h);
            }
            *(u16x4*)(pix + mt * 16 + quad * 4) = pk;
        }
    }
}

// ---------------------------------------------------------------------------
// Kernel 6: out = addin + gate * conv3x3(hmid, w2[e])  (-> NCHW fp32).
// ---------------------------------------------------------------------------
__global__ __launch_bounds__(256, 3) void conv2_kernel(
    const unsigned short* __restrict__ hmid, const unsigned short* __restrict__ w2f,
    const int* __restrict__ eidx, const float* __restrict__ gate, int slot,
    const float* __restrict__ addin, float* __restrict__ out)
{
    __shared__ __align__(16) char smem[LDSBYTES];
    int ox0 = blockIdx.x * TILE, oy0 = blockIdx.y * TILE, b = blockIdx.z;
    int e = __builtin_amdgcn_readfirstlane(eidx[b * 2 + slot]);
    float gv = __uint_as_float(
        __builtin_amdgcn_readfirstlane(__float_as_uint(gate[b * 2 + slot])));

    stage_nhwc_bf16(hmid, b, oy0, ox0, smem);
    __syncthreads();

    f32x4 acc[4][3];
    conv_core(smem, w2f + (size_t)e * FRAG_ELEMS, acc);

    const int lane = threadIdx.x & 63;
    const int wv = threadIdx.x >> 6;
    const int n = lane & 15, quad = lane >> 4;
#pragma unroll
    for (int g = 0; g < 4; ++g) {
        int row = oy0 + wv * 4 + g;
#pragma unroll
        for (int mt = 0; mt < 3; ++mt)
#pragma unroll
            for (int r = 0; r < 4; ++r) {
                int oc = mt * 16 + quad * 4 + r;
                size_t idx = (((size_t)b * CH + oc) << 16) + (row << 8) + ox0 + n;
                out[idx] = addin[idx] + gv * acc[g][mt][r];
            }
    }
}

// ---------------------------------------------------------------------------
extern "C" void kernel_launch(void* const* d_in, const int* in_sizes, int n_in,
                              void* d_out, int out_size, void* d_ws, size_t ws_size,
                              hipStream_t stream) {
    (void)in_sizes; (void)n_in; (void)out_size; (void)ws_size;
    const float* x          = (const float*)d_in[0];
    const float* P_hat      = (const float*)d_in[1];
    const float* proj_a_w   = (const float*)d_in[2];
    const float* proj_b_w   = (const float*)d_in[3];
    const float* dw_b_w     = (const float*)d_in[4];
    const float* fi_align_w = (const float*)d_in[5];
    const float* expert_w1  = (const float*)d_in[6];
    const float* expert_w2  = (const float*)d_in[7];
    const float* router_w   = (const float*)d_in[8];
    const float* router_b   = (const float*)d_in[9];
    float* out = (float*)d_out;

    char* ws = (char*)d_ws;
    unsigned short* Fx   = (unsigned short*)ws;                    // 50,331,648 B
    unsigned short* hmid = (unsigned short*)(ws + 50331648);       // 50,331,648 B
    unsigned short* wfxf = (unsigned short*)(ws + 100663296);      // 442,368 B
    unsigned short* w1f  = (unsigned short*)(ws + 100663296 + 442368);
    unsigned short* w2f  = (unsigned short*)(ws + 100663296 + 2 * 442368);
    float* gap  = (float*)(ws + 100663296 + 3 * 442368);           // 1536 B
    float* gate = gap + BATCH * CH;
    int*   eidx = (int*)(gate + BATCH * 2);

    precompute_kernel<<<dim3(BATCH), 256, 0, stream>>>(
        P_hat, proj_a_w, proj_b_w, dw_b_w, fi_align_w, wfxf, gap);

    repack_kernel<<<dim3(NEXP, 2), 256, 0, stream>>>(
        expert_w1, expert_w2, w1f, w2f);

    fxconv_kernel<<<dim3(16, 16, BATCH), 256, 0, stream>>>(x, wfxf, Fx, gap);

    route_kernel<<<dim3(1), 64, 0, stream>>>(gap, router_w, router_b, gate, eidx);

    conv1_kernel<<<dim3(16, 16, BATCH), 256, 0, stream>>>(Fx, w1f, eidx, 0, hmid);
    conv2_kernel<<<dim3(16, 16, BATCH), 256, 0, stream>>>(hmid, w2f, eidx, gate, 0, x, out);
    conv1_kernel<<<dim3(16, 16, BATCH), 256, 0, stream>>>(Fx, w1f, eidx, 1, hmid);
    conv2_kernel<<<dim3(16, 16, BATCH), 256, 0, stream>>>(hmid, w2f, eidx, gate, 1, out, out);
}

// Round 4
// 715.263 us; speedup vs baseline: 7.6094x; 1.1249x over previous
//
#include <hip/hip_runtime.h>
#include <hip/hip_bf16.h>
#include <math.h>

#define BATCH 8
#define CH 48
#define HH 256
#define WW 256
#define NPROMPT 16
#define NEXP 8
#define NGRP 4
#define GDIM 12
#define HW (HH * WW)

// MFMA A-fragment tables: [tap(9)][mtile(3)][kblock(2)][lane(64)][j(8)] bf16
// value = W[oc = mt*16 + (lane&15)][cin = kb*32 + (lane>>4)*8 + j][tap], 0 for cin>=48
#define FRAG_ELEMS (9 * 3 * 2 * 64 * 8)   // 27648 elems = 55296 B per (image|expert)
#define FRAG_BYTES (FRAG_ELEMS * 2)

typedef short bf16x8 __attribute__((ext_vector_type(8)));   // 8 bf16 (4 VGPRs)
typedef float f32x4  __attribute__((ext_vector_type(4)));
typedef unsigned short u16x4 __attribute__((ext_vector_type(4)));

#define TILE 16
#define ITILE 18
#define NPIX (ITILE * ITILE)        // 324
#define PIXB 128                    // LDS bytes/pixel (8 slots x 16B, swizzled)
#define LDSPIX 328                  // padded so DMA item count = 41*64
#define LDSBYTES (LDSPIX * PIXB)    // 41984
#define GPIXB 96                    // global NHWC-48 bf16 bytes/pixel
#define IMGB ((size_t)HW * GPIXB)   // 6291456 B per image

__device__ __forceinline__ unsigned short f2bf(float f) {
    unsigned u = __float_as_uint(f);
    unsigned r = (u + 0x7FFFu + ((u >> 16) & 1u)) >> 16;   // RNE
    return (unsigned short)r;
}

// async global->LDS DMA, 16B per lane; lds dest = uniform base + lane*16
__device__ __forceinline__ void load_lds16(const void* g, void* l) {
    __builtin_amdgcn_global_load_lds(
        (const __attribute__((address_space(1))) unsigned int*)g,
        (__attribute__((address_space(3))) unsigned int*)l, 16, 0, 0);
}

// ---------------------------------------------------------------------------
// Kernel 1: fold branch-a + branch-b into per-image 3x3 weights in MFMA
// A-fragment layout. Also zero gap accumulator and the DMA zero-page.
// ---------------------------------------------------------------------------
__global__ __launch_bounds__(256) void precompute_kernel(
    const float* __restrict__ P_hat,
    const float* __restrict__ proj_a_w,
    const float* __restrict__ proj_b_w,
    const float* __restrict__ dw_b_w,
    const float* __restrict__ fi_align_w,
    unsigned short* __restrict__ wfxf,
    float* __restrict__ gap,
    float* __restrict__ zpage)
{
    int b = blockIdx.x;
    int tid = threadIdx.x;
    __shared__ float p_avg[CH];
    __shared__ float W_fi[NGRP * CH];
    __shared__ float W_a[CH * CH];

    if (tid < CH) {
        float s = 0.f;
        for (int n = 0; n < NPROMPT; n++)
            s += P_hat[(b * NPROMPT + n) * CH + tid];
        p_avg[tid] = s * (1.0f / NPROMPT);
    }
    if (b == 0) {
        for (int i = tid; i < BATCH * CH; i += 256) gap[i] = 0.f;
        if (tid < 64) zpage[tid] = 0.f;   // 256 B zero page
    }
    __syncthreads();

    if (tid < NGRP * CH) {
        int g = tid / CH, k = tid % CH;
        float s = 0.f;
        for (int j = 0; j < GDIM; j++) {
            int c = g * GDIM + j;
            s += p_avg[c] * proj_a_w[c * CH + k];
        }
        W_fi[tid] = s;
    }
    __syncthreads();

    for (int e = tid; e < CH * CH; e += 256) {
        int o = e / CH, k = e % CH;
        float s = 0.f;
        for (int g = 0; g < NGRP; g++)
            s += fi_align_w[o * NGRP + g] * W_fi[g * CH + k];
        W_a[e] = s;
    }
    __syncthreads();

    for (int i = tid; i < FRAG_ELEMS; i += 256) {
        int j = i & 7;
        int lane = (i >> 3) & 63;
        int blk = i >> 9;            // (tap*3+mt)*2+kb
        int kb = blk & 1;
        int tmp = blk >> 1;
        int mt = tmp % 3, tap = tmp / 3;
        int oc = mt * 16 + (lane & 15);
        int cin = kb * 32 + (lane >> 4) * 8 + j;
        float v = 0.f;
        if (cin < CH) {
            v = dw_b_w[oc * 9 + tap] * proj_b_w[oc * CH + cin];
            if (tap == 4) v += W_a[oc * CH + cin];
        }
        wfxf[(size_t)b * FRAG_ELEMS + i] = f2bf(v);
    }
}

// ---------------------------------------------------------------------------
// Kernel 2: repack expert weights into MFMA A-fragment layout.
// ---------------------------------------------------------------------------
__global__ __launch_bounds__(256) void repack_kernel(
    const float* __restrict__ w1, const float* __restrict__ w2,
    unsigned short* __restrict__ w1f, unsigned short* __restrict__ w2f)
{
    int e = blockIdx.x;
    const float* src = blockIdx.y ? w2 : w1;
    unsigned short* dst = blockIdx.y ? w2f : w1f;
    for (int i = threadIdx.x; i < FRAG_ELEMS; i += 256) {
        int j = i & 7;
        int lane = (i >> 3) & 63;
        int blk = i >> 9;
        int kb = blk & 1;
        int tmp = blk >> 1;
        int mt = tmp % 3, tap = tmp / 3;
        int oc = mt * 16 + (lane & 15);
        int cin = kb * 32 + (lane >> 4) * 8 + j;
        float v = (cin < CH) ? src[(((size_t)e * CH + oc) * CH + cin) * 9 + tap] : 0.f;
        dst[(size_t)e * FRAG_ELEMS + i] = f2bf(v);
    }
}

// ---------------------------------------------------------------------------
// Kernel 3: transpose x NCHW fp32 -> dense NHWC-48 bf16 (96 B/pixel).
// Block = 64 consecutive pixels (one W-row chunk) x all 48 channels.
// ---------------------------------------------------------------------------
__global__ __launch_bounds__(256) void transpose_kernel(
    const float* __restrict__ x, unsigned short* __restrict__ xT)
{
    __shared__ float t[CH * 65];
    int pix0 = blockIdx.x * 64;
    int b = pix0 >> 16;
    int rem = pix0 & 65535;
    int tid = threadIdx.x;
    int px = tid & 63, c0 = tid >> 6;

    float v[12];
#pragma unroll
    for (int k = 0; k < 12; k++)
        v[k] = x[(((size_t)(b * CH + c0 + 4 * k)) << 16) + rem + px];
#pragma unroll
    for (int k = 0; k < 12; k++)
        t[(c0 + 4 * k) * 65 + px] = v[k];
    __syncthreads();

#pragma unroll
    for (int k = 0; k < 2; k++) {
        int w = tid + 256 * k;
        if (w < 384) {
            int p2 = w / 6, o = w % 6;
            bf16x8 pk;
#pragma unroll
            for (int j = 0; j < 8; j++)
                pk[j] = (short)f2bf(t[(o * 8 + j) * 65 + p2]);
            *(bf16x8*)((char*)xT + (size_t)pix0 * GPIXB + (size_t)w * 16) = pk;
        }
    }
}

// ---------------------------------------------------------------------------
// DMA staging: LDS[p][slot] (PIXB=128) <- global dense NHWC-48 (96B/pixel).
// LDS slot o of pixel p holds channel-octet m = o ^ (gx&7)  (swizzle in LDS
// only -> conflict-free ds_read_b128). OOB pixels / pad octets <- zero page.
// ---------------------------------------------------------------------------
__device__ __forceinline__ void stage_swz(
    const char* __restrict__ srcimg, int oy0, int ox0,
    char* smem, const char* __restrict__ zp)
{
    int wv = threadIdx.x >> 6, lane = threadIdx.x & 63;
    for (int k = wv; k < 41; k += 4) {
        int w = k * 64 + lane;
        int px = w >> 3, o = w & 7;
        int yy = px / ITILE, xx = px - yy * ITILE;
        int gy = oy0 + yy - 1, gx = ox0 + xx - 1;
        int m = o ^ (gx & 7);
        const char* g = zp;
        if (px < NPIX && (unsigned)gy < 256u && (unsigned)gx < 256u && m < 6)
            g = srcimg + (size_t)((gy << 8) + gx) * GPIXB + m * 16;
        load_lds16(g, smem + k * 1024);
    }
}

// ---------------------------------------------------------------------------
// Core: 9-tap K=64 MFMA GEMM. M=48 (3 mtiles), N=16 px/row, 4 rows per wave.
// A-frags double-buffered across taps; B reads swizzle-indexed (2-way free).
// ---------------------------------------------------------------------------
template <bool ACC>
__device__ __forceinline__ void conv_core(
    const char* smem, const unsigned short* __restrict__ wfrag,
    int ox0, f32x4 acc[4][3])
{
    const int lane = threadIdx.x & 63;
    const int wv = threadIdx.x >> 6;
    const int n = lane & 15;
    const int quad = lane >> 4;
    const bf16x8* wp = (const bf16x8*)wfrag;

    if (!ACC) {
#pragma unroll
        for (int g = 0; g < 4; ++g)
#pragma unroll
            for (int mt = 0; mt < 3; ++mt)
                acc[g][mt] = (f32x4){0.f, 0.f, 0.f, 0.f};
    }

    // per-dx lane-dependent column offsets (kb0 and kb1 slots)
    int colb0[3], colb1[3];
#pragma unroll
    for (int dx = 0; dx < 3; ++dx) {
        int key = (ox0 - 1 + dx + n) & 7;
        colb0[dx] = (dx + n) * PIXB + ((quad ^ key) * 16);
        colb1[dx] = (dx + n) * PIXB + (((quad + 4) ^ key) * 16);
    }

    bf16x8 a[2][6];
#pragma unroll
    for (int mt = 0; mt < 3; ++mt) {
        a[0][mt]     = wp[(mt * 2 + 0) * 64 + lane];
        a[0][mt + 3] = wp[(mt * 2 + 1) * 64 + lane];
    }

#pragma unroll
    for (int tap = 0; tap < 9; ++tap) {
        const int cur = tap & 1;
        if (tap < 8) {
#pragma unroll
            for (int mt = 0; mt < 3; ++mt) {
                a[cur ^ 1][mt]     = wp[(((tap + 1) * 3 + mt) * 2 + 0) * 64 + lane];
                a[cur ^ 1][mt + 3] = wp[(((tap + 1) * 3 + mt) * 2 + 1) * 64 + lane];
            }
        }
        const int dy = tap / 3, dx = tap % 3;
#pragma unroll
        for (int g = 0; g < 4; ++g) {
            const int rowb = (wv * 4 + g + dy) * (ITILE * PIXB);
            bf16x8 b0 = *(const bf16x8*)(smem + rowb + colb0[dx]);
            bf16x8 b1 = *(const bf16x8*)(smem + rowb + colb1[dx]);
            acc[g][0] = __builtin_amdgcn_mfma_f32_16x16x32_bf16(a[cur][0], b0, acc[g][0], 0, 0, 0);
            acc[g][1] = __builtin_amdgcn_mfma_f32_16x16x32_bf16(a[cur][1], b0, acc[g][1], 0, 0, 0);
            acc[g][2] = __builtin_amdgcn_mfma_f32_16x16x32_bf16(a[cur][2], b0, acc[g][2], 0, 0, 0);
            acc[g][0] = __builtin_amdgcn_mfma_f32_16x16x32_bf16(a[cur][3], b1, acc[g][0], 0, 0, 0);
            acc[g][1] = __builtin_amdgcn_mfma_f32_16x16x32_bf16(a[cur][4], b1, acc[g][1], 0, 0, 0);
            acc[g][2] = __builtin_amdgcn_mfma_f32_16x16x32_bf16(a[cur][5], b1, acc[g][2], 0, 0, 0);
        }
    }
}

// dense NHWC-48 bf16 store of one conv result (oc channels of pixel col n)
__device__ __forceinline__ void store_pix(
    char* __restrict__ dstimg, int row, int col, int quad,
    const f32x4 v[3])
{
    size_t pb = (size_t)((row << 8) + col) * GPIXB;
#pragma unroll
    for (int mt = 0; mt < 3; ++mt) {
        u16x4 pk;
#pragma unroll
        for (int r = 0; r < 4; ++r) pk[r] = f2bf(v[mt][r]);
        *(u16x4*)(dstimg + pb + mt * 32 + quad * 8) = pk;
    }
}

// ---------------------------------------------------------------------------
// Kernel 4: Fx = conv3x3(xT, Wfx[b]) -> dense NHWC bf16, + fused GAP.
// ---------------------------------------------------------------------------
__global__ __launch_bounds__(256, 3) void fxconv_kernel(
    const unsigned short* __restrict__ xT, const unsigned short* __restrict__ wfxf,
    unsigned short* __restrict__ Fx, float* __restrict__ gap,
    const float* __restrict__ zp)
{
    __shared__ __align__(16) char smem[LDSBYTES];
    int ox0 = blockIdx.x * TILE, oy0 = blockIdx.y * TILE, b = blockIdx.z;

    stage_swz((const char*)xT + (size_t)b * IMGB, oy0, ox0, smem, (const char*)zp);
    __syncthreads();

    f32x4 acc[4][3];
    conv_core<false>(smem, wfxf + (size_t)b * FRAG_ELEMS, ox0, acc);

    const int lane = threadIdx.x & 63;
    const int wv = threadIdx.x >> 6;
    const int n = lane & 15, quad = lane >> 4;
    char* dimg = (char*)Fx + (size_t)b * IMGB;

    float gsum[3][4];
#pragma unroll
    for (int mt = 0; mt < 3; ++mt)
#pragma unroll
        for (int r = 0; r < 4; ++r) gsum[mt][r] = 0.f;

#pragma unroll
    for (int g = 0; g < 4; ++g) {
        int row = oy0 + wv * 4 + g;
        store_pix(dimg, row, ox0 + n, quad, acc[g]);
#pragma unroll
        for (int mt = 0; mt < 3; ++mt)
#pragma unroll
            for (int r = 0; r < 4; ++r) gsum[mt][r] += acc[g][mt][r];
    }
#pragma unroll
    for (int mt = 0; mt < 3; ++mt)
#pragma unroll
        for (int r = 0; r < 4; ++r) {
            float v = gsum[mt][r];
            v += __shfl_xor(v, 1);
            v += __shfl_xor(v, 2);
            v += __shfl_xor(v, 4);
            v += __shfl_xor(v, 8);
            if (n == 0)
                atomicAdd(&gap[b * CH + mt * 16 + quad * 4 + r], v);
        }
}

// ---------------------------------------------------------------------------
// Kernel 5: routing.
// ---------------------------------------------------------------------------
__global__ void route_kernel(
    const float* __restrict__ gap,
    const float* __restrict__ router_w,
    const float* __restrict__ router_b,
    float* __restrict__ gate, int* __restrict__ eidx)
{
    int b = threadIdx.x;
    if (b >= BATCH) return;
    float sc[NEXP];
    for (int e = 0; e < NEXP; e++) {
        float s = router_b[e];
        for (int c = 0; c < CH; c++)
            s += (gap[b * CH + c] * (1.0f / HW)) * router_w[e * CH + c];
        sc[e] = s;
    }
    float v0 = -1e30f, v1 = -1e30f;
    int i0 = 0, i1 = 0;
    for (int e = 0; e < NEXP; e++) {
        if (sc[e] > v0) { v1 = v0; i1 = i0; v0 = sc[e]; i0 = e; }
        else if (sc[e] > v1) { v1 = sc[e]; i1 = e; }
    }
    float ex = expf(v1 - v0);
    float denom = 1.0f / (1.0f + ex);
    gate[b * 2 + 0] = denom;
    gate[b * 2 + 1] = ex * denom;
    eidx[b * 2 + 0] = i0;
    eidx[b * 2 + 1] = i1;
}

// ---------------------------------------------------------------------------
// Kernel 6: w2s[b][slot] = gate[b][slot] * w2f[eidx[b][slot]]  (A-frag bf16).
// ---------------------------------------------------------------------------
__global__ __launch_bounds__(256) void scale_kernel(
    const unsigned short* __restrict__ w2f, const float* __restrict__ gate,
    const int* __restrict__ eidx, unsigned short* __restrict__ w2s)
{
    int b = blockIdx.x, s = blockIdx.y;
    int e = eidx[b * 2 + s];
    float g = gate[b * 2 + s];
    const unsigned short* src = w2f + (size_t)e * FRAG_ELEMS;
    unsigned short* dst = w2s + (size_t)(b * 2 + s) * FRAG_ELEMS;
    for (int i = threadIdx.x; i < FRAG_ELEMS; i += 256) {
        float v = __uint_as_float((unsigned)src[i] << 16);
        dst[i] = f2bf(v * g);
    }
}

// ---------------------------------------------------------------------------
// Kernel 7: both routed experts' conv1 from ONE staged Fx tile:
//   hmid_s = gelu(conv3x3(Fx, w1[e_s])), s = 0,1.
// ---------------------------------------------------------------------------
__global__ __launch_bounds__(256, 3) void conv1_both_kernel(
    const unsigned short* __restrict__ Fx, const unsigned short* __restrict__ w1f,
    const int* __restrict__ eidx, const float* __restrict__ zp,
    unsigned short* __restrict__ hmid0, unsigned short* __restrict__ hmid1)
{
    __shared__ __align__(16) char smem[LDSBYTES];
    int ox0 = blockIdx.x * TILE, oy0 = blockIdx.y * TILE, b = blockIdx.z;

    stage_swz((const char*)Fx + (size_t)b * IMGB, oy0, ox0, smem, (const char*)zp);
    __syncthreads();

    const int lane = threadIdx.x & 63;
    const int wv = threadIdx.x >> 6;
    const int n = lane & 15, quad = lane >> 4;

    f32x4 acc[4][3];
#pragma unroll
    for (int s = 0; s < 2; ++s) {
        int e = __builtin_amdgcn_readfirstlane(eidx[b * 2 + s]);
        conv_core<false>(smem, w1f + (size_t)e * FRAG_ELEMS, ox0, acc);
        char* dimg = (char*)(s ? hmid1 : hmid0) + (size_t)b * IMGB;
#pragma unroll
        for (int g = 0; g < 4; ++g) {
            int row = oy0 + wv * 4 + g;
            f32x4 h[3];
#pragma unroll
            for (int mt = 0; mt < 3; ++mt)
#pragma unroll
                for (int r = 0; r < 4; ++r) {
                    float a = acc[g][mt][r];
                    h[mt][r] = 0.5f * a * (1.0f + erff(a * 0.70710678118654752f));
                }
            store_pix(dimg, row, ox0 + n, quad, h);
        }
    }
}

// ---------------------------------------------------------------------------
// Kernel 8: out = x + conv3x3(hmid0, g0*w2[e0]) + conv3x3(hmid1, g1*w2[e1]).
// Stages hmid0 then hmid1 into the same LDS tile; acc persists in registers.
// ---------------------------------------------------------------------------
__global__ __launch_bounds__(256, 3) void conv2_both_kernel(
    const unsigned short* __restrict__ hmid0, const unsigned short* __restrict__ hmid1,
    const unsigned short* __restrict__ w2s, const float* __restrict__ zp,
    const float* __restrict__ x, float* __restrict__ out)
{
    __shared__ __align__(16) char smem[LDSBYTES];
    int ox0 = blockIdx.x * TILE, oy0 = blockIdx.y * TILE, b = blockIdx.z;

    f32x4 acc[4][3];

    stage_swz((const char*)hmid0 + (size_t)b * IMGB, oy0, ox0, smem, (const char*)zp);
    __syncthreads();
    conv_core<false>(smem, w2s + (size_t)(b * 2 + 0) * FRAG_ELEMS, ox0, acc);
    __syncthreads();   // all waves done reading before re-stage

    stage_swz((const char*)hmid1 + (size_t)b * IMGB, oy0, ox0, smem, (const char*)zp);
    __syncthreads();
    conv_core<true>(smem, w2s + (size_t)(b * 2 + 1) * FRAG_ELEMS, ox0, acc);

    const int lane = threadIdx.x & 63;
    const int wv = threadIdx.x >> 6;
    const int n = lane & 15, quad = lane >> 4;
#pragma unroll
    for (int g = 0; g < 4; ++g) {
        int row = oy0 + wv * 4 + g;
#pragma unroll
        for (int mt = 0; mt < 3; ++mt)
#pragma unroll
            for (int r = 0; r < 4; ++r) {
                int oc = mt * 16 + quad * 4 + r;
                size_t idx = (((size_t)b * CH + oc) << 16) + (row << 8) + ox0 + n;
                out[idx] = x[idx] + acc[g][mt][r];
            }
    }
}

// ---------------------------------------------------------------------------
extern "C" void kernel_launch(void* const* d_in, const int* in_sizes, int n_in,
                              void* d_out, int out_size, void* d_ws, size_t ws_size,
                              hipStream_t stream) {
    (void)in_sizes; (void)n_in; (void)out_size; (void)ws_size;
    const float* x          = (const float*)d_in[0];
    const float* P_hat      = (const float*)d_in[1];
    const float* proj_a_w   = (const float*)d_in[2];
    const float* proj_b_w   = (const float*)d_in[3];
    const float* dw_b_w     = (const float*)d_in[4];
    const float* fi_align_w = (const float*)d_in[5];
    const float* expert_w1  = (const float*)d_in[6];
    const float* expert_w2  = (const float*)d_in[7];
    const float* router_w   = (const float*)d_in[8];
    const float* router_b   = (const float*)d_in[9];
    float* out = (float*)d_out;

    // d_out doubles as scratch before the final conv2 pass overwrites it:
    //   [0, 50331648)        Fx (bf16 NHWC-48)
    //   [62914560, +1327104) wfxf / w1f / w2f fragment tables
    char* ob = (char*)d_out;
    unsigned short* Fx   = (unsigned short*)ob;
    unsigned short* wfxf = (unsigned short*)(ob + 62914560);
    unsigned short* w1f  = (unsigned short*)(ob + 62914560 + FRAG_BYTES * NEXP);
    unsigned short* w2f  = (unsigned short*)(ob + 62914560 + 2 * FRAG_BYTES * NEXP);

    // ws: xT (aliased by hmid1 after fxconv) | hmid0 | w2s | zpage | gap | gate | eidx
    char* ws = (char*)d_ws;
    unsigned short* xT    = (unsigned short*)ws;               // 50331648 B
    unsigned short* hmid1 = (unsigned short*)ws;               // alias (xT dead)
    unsigned short* hmid0 = (unsigned short*)(ws + 50331648);  // 50331648 B
    unsigned short* w2s   = (unsigned short*)(ws + 100663296); // 884736 B
    float* zp   = (float*)(ws + 100663296 + 884736);           // 256 B
    float* gap  = (float*)(ws + 100663296 + 884736 + 256);     // 1536 B
    float* gate = gap + BATCH * CH;                            // 64 B
    int*   eidx = (int*)(gate + BATCH * 2);                    // 64 B

    precompute_kernel<<<dim3(BATCH), 256, 0, stream>>>(
        P_hat, proj_a_w, proj_b_w, dw_b_w, fi_align_w, wfxf, gap, zp);

    repack_kernel<<<dim3(NEXP, 2), 256, 0, stream>>>(
        expert_w1, expert_w2, w1f, w2f);

    transpose_kernel<<<dim3(BATCH * HW / 64), 256, 0, stream>>>(x, xT);

    fxconv_kernel<<<dim3(16, 16, BATCH), 256, 0, stream>>>(xT, wfxf, Fx, gap, zp);

    route_kernel<<<dim3(1), 64, 0, stream>>>(gap, router_w, router_b, gate, eidx);

    scale_kernel<<<dim3(BATCH, 2), 256, 0, stream>>>(w2f, gate, eidx, w2s);

    conv1_both_kernel<<<dim3(16, 16, BATCH), 256, 0, stream>>>(
        Fx, w1f, eidx, zp, hmid0, hmid1);

    conv2_both_kernel<<<dim3(16, 16, BATCH), 256, 0, stream>>>(
        hmid0, hmid1, w2s, zp, x, out);
}